// Round 12
// baseline (81.108 us; speedup 1.0000x reference)
//
#include <hip/hip_runtime.h>
#include <hip/hip_bf16.h>

#define N_NODES 50000
#define N_EDGES 800000
#define IN_DIM 128
#define OUT_DIM 64
#define REL_DIM 32
#define NEG_SLOPE 0.01f
#define NB 391            // coarse buckets: 128 dst nodes each (391*128 = 50048)
#define K3_TILE 2048
#define K3_BLOCKS ((N_EDGES + K3_TILE - 1) / K3_TILE)   // 391
#define BWIN 2560         // fixed per-bucket window (Poisson(2048): max over 391 ~ 2200)
#define NBLK_A 782        // role-A blocks: ceil(50000/64)
#define K12_GRID 2346     // 3*NBLK_A; role A = blockIdx%3==0, else role B (1564 blocks)

// ================= K12 fused: GEMM (role A) || contiguous p-stream dotp (role B) ==============
// Role A: z = h @ Wfc^T register-tiled, K-quarter LDS tiles (17.4 KB -> 8 blocks/CU).
// Role B: dotp[e] = wp . p[e] via lane-contiguous float4 stream + shfl8 reduce +
//         in-wave 8x8 transpose for one full-lane coalesced store per half.
__global__ __launch_bounds__(256, 8) void k12_fused(const float* __restrict__ h,
                                                    const float* __restrict__ Wfc,
                                                    const float* __restrict__ Wattn,
                                                    const float* __restrict__ p,
                                                    __hip_bfloat16* __restrict__ zb,
                                                    float* __restrict__ s1,
                                                    float* __restrict__ s2,
                                                    float* __restrict__ dotp,
                                                    unsigned* __restrict__ ccur) {
    __shared__ float Wl[32][68];   // role A: [k_local][c]   (K-quarter)
    __shared__ float hl[32][68];   // role A: [k_local][n]
    const int t = threadIdx.x;
    const int b = blockIdx.x;

    if (b % 3 == 0) {
        // ---------------- role A: GEMM (4 K-quarters of 32) ----------------
        const int blk = b / 3;
        const int cg = t & 15, ng = t >> 4;
        const int c0 = cg * 4;
        float wa1[4], wa2[4];
#pragma unroll
        for (int j = 0; j < 4; ++j) { wa1[j] = Wattn[c0 + j]; wa2[j] = Wattn[96 + c0 + j]; }

        const int n0 = blk * 64;
        float acc[4][4] = {};
        const float4* W4 = (const float4*)Wfc;   // [64][32] float4
        const float4* h4 = (const float4*)h;     // [N][32] float4

#pragma unroll
        for (int Q = 0; Q < 4; ++Q) {
            __syncthreads();   // protect LDS from previous quarter's readers
#pragma unroll
            for (int i = 0; i < 2; ++i) {
                int idx = t + 256 * i;               // 0..511
                int c = idx & 63, k4l = idx >> 6;    // wave: 64 consecutive c, uniform k4l
                float4 v = W4[c * 32 + Q * 8 + k4l];
                Wl[4*k4l+0][c] = v.x; Wl[4*k4l+1][c] = v.y;
                Wl[4*k4l+2][c] = v.z; Wl[4*k4l+3][c] = v.w;
            }
#pragma unroll
            for (int i = 0; i < 2; ++i) {
                int idx = t + 256 * i;
                int n = idx & 63, k4l = idx >> 6;
                int gn = n0 + n; if (gn > N_NODES - 1) gn = N_NODES - 1;
                float4 v = h4[(size_t)gn * 32 + Q * 8 + k4l];
                hl[4*k4l+0][n] = v.x; hl[4*k4l+1][n] = v.y;
                hl[4*k4l+2][n] = v.z; hl[4*k4l+3][n] = v.w;
            }
            __syncthreads();
#pragma unroll 8
            for (int k = 0; k < 32; ++k) {
                float4 wv = *(const float4*)&Wl[k][c0];
                float4 hv = *(const float4*)&hl[k][ng * 4];
                float wvf[4] = {wv.x, wv.y, wv.z, wv.w};
                float hvf[4] = {hv.x, hv.y, hv.z, hv.w};
#pragma unroll
                for (int i = 0; i < 4; ++i)
#pragma unroll
                    for (int j = 0; j < 4; ++j) acc[i][j] += hvf[i] * wvf[j];
            }
        }

#pragma unroll
        for (int i = 0; i < 4; ++i) {
            int gn = n0 + ng * 4 + i;
            float r1 = acc[i][0]*wa1[0] + acc[i][1]*wa1[1] + acc[i][2]*wa1[2] + acc[i][3]*wa1[3];
            float r2 = acc[i][0]*wa2[0] + acc[i][1]*wa2[1] + acc[i][2]*wa2[2] + acc[i][3]*wa2[3];
#pragma unroll
            for (int off = 1; off < 16; off <<= 1) {
                r1 += __shfl_xor(r1, off, 64);
                r2 += __shfl_xor(r2, off, 64);
            }
            if (gn < N_NODES) {
                __hip_bfloat16 b0 = __float2bfloat16(acc[i][0]);
                __hip_bfloat16 b1 = __float2bfloat16(acc[i][1]);
                __hip_bfloat16 b2 = __float2bfloat16(acc[i][2]);
                __hip_bfloat16 b3 = __float2bfloat16(acc[i][3]);
                ushort4 st;
                st.x = *(unsigned short*)&b0; st.y = *(unsigned short*)&b1;
                st.z = *(unsigned short*)&b2; st.w = *(unsigned short*)&b3;
                ((ushort4*)zb)[(size_t)gn * 16 + cg] = st;
                if (cg == 0) { s1[gn] = r1; s2[gn] = r2; }
            }
        }
    } else {
        // ---------------- role B: contiguous dotp stream ----------------
        const int kb = b - b / 3 - 1;          // 0..1563
        if (kb == 0) {
            for (int i = t; i < NB * 16; i += 256) ccur[i] = 0u;
        }
        const int lane = t & 63;
        const int tid = kb * 256 + t;          // 0..400383
        const int a0 = (kb * 256 + (t & ~63)) >> 3;   // wave's base edge-slot (8 per wave)
        if (a0 < 50000) {                      // whole-wave guard (a0..a0+7 all < 50000)
            const int q = tid & 7;
            const float w0 = Wattn[64 + q * 4 + 0];
            const float w1 = Wattn[64 + q * 4 + 1];
            const float w2 = Wattn[64 + q * 4 + 2];
            const float w3 = Wattn[64 + q * 4 + 3];
            const float4* p4 = (const float4*)p;
#pragma unroll
            for (int half = 0; half < 2; ++half) {
                float4 v[8];
#pragma unroll
                for (int j = 0; j < 8; ++j) v[j] = p4[tid + (half * 8 + j) * 400000];
                float d[8];
#pragma unroll
                for (int j = 0; j < 8; ++j)
                    d[j] = v[j].x * w0 + v[j].y * w1 + v[j].z * w2 + v[j].w * w3;
#pragma unroll
                for (int off = 1; off < 8; off <<= 1)
#pragma unroll
                    for (int j = 0; j < 8; ++j) d[j] += __shfl_xor(d[j], off, 64);
                // in-wave 8x8 transpose: lane l takes d[l>>3] from group (l&7)
                float val = 0.f;
#pragma unroll
                for (int j = 0; j < 8; ++j) {
                    float tmp = __shfl(d[j], (lane & 7) * 8, 64);
                    if ((lane >> 3) == j) val = tmp;
                }
                // one coalesced store: 8-lane groups write 32B-contiguous segments
                dotp[a0 + (lane & 7) + (half * 8 + (lane >> 3)) * 50000] = val;
            }
        }
    }
}

// ================= K3: logit assembly + leaky-relu + binning into fixed bucket windows ========
// pair item: (ev, aux) with aux = src | (d_local << 16)
__global__ __launch_bounds__(256) void k3_fused(const float* __restrict__ dotp,
                                                const int* __restrict__ src,
                                                const int* __restrict__ dst,
                                                const float* __restrict__ s1,
                                                const float* __restrict__ s2,
                                                unsigned* __restrict__ ccur,
                                                float2* __restrict__ pair) {
    __shared__ unsigned hist[NB];
    __shared__ unsigned gb[NB];
    __shared__ unsigned lcur[NB];
    const int t = threadIdx.x;
    for (int i = t; i < NB; i += 256) hist[i] = 0;
    __syncthreads();

    const int base = blockIdx.x * K3_TILE;
    float evr[8];
    unsigned auxr[8];
    short br[8];
#pragma unroll
    for (int i = 0; i < 8; ++i) {
        int e = base + i * 256 + t;
        if (e < N_EDGES) {
            int s = src[e], d = dst[e];
            float a = s1[s] + dotp[e] + s2[d];
            evr[i] = a > 0.f ? a : NEG_SLOPE * a;
            auxr[i] = (unsigned)s | ((unsigned)(d & 127) << 16);
            int bb = d >> 7;
            br[i] = (short)bb;
            atomicAdd(&hist[bb], 1u);
        } else br[i] = -1;
    }
    __syncthreads();
    for (int i = t; i < NB; i += 256) {
        lcur[i] = 0;
        gb[i] = hist[i] ? (i * BWIN + atomicAdd(&ccur[i * 16], hist[i])) : 0u;
    }
    __syncthreads();
#pragma unroll
    for (int i = 0; i < 8; ++i) {
        if (br[i] >= 0) {
            int bb = br[i];
            unsigned pos = atomicAdd(&lcur[bb], 1u);
            pair[gb[bb] + pos] = make_float2(evr[i], __uint_as_float(auxr[i]));
        }
    }
}

// ================= K3b: within-bucket sort to per-node order + per-node beg/end ===============
__global__ __launch_bounds__(256) void k3b_sort(const unsigned* __restrict__ ccur,
                                                const float2* __restrict__ pair,
                                                float2* __restrict__ pair2,
                                                unsigned* __restrict__ beg_g,
                                                unsigned* __restrict__ end_g) {
    __shared__ float2 items[BWIN];          // 20.5KB
    __shared__ unsigned hist[128], loffs[128], lcur[128], sd[128];
    const int t = threadIdx.x;
    const int b = blockIdx.x;
    const int base = b * BWIN;
    int cnt = (int)ccur[b * 16];
    if (cnt > BWIN) cnt = BWIN;             // safety clamp (deterministic input: never hit)
    if (t < 128) { hist[t] = 0; lcur[t] = 0; }
    __syncthreads();
    for (int i = t; i < cnt; i += 256) {
        float2 it = pair[base + i];
        items[i] = it;
        atomicAdd(&hist[__float_as_uint(it.y) >> 16], 1u);
    }
    __syncthreads();
    unsigned v = (t < 128) ? hist[t] : 0u;
    if (t < 128) sd[t] = v;
    __syncthreads();
#pragma unroll
    for (int off = 1; off < 128; off <<= 1) {
        unsigned tmp = (t >= off && t < 128) ? sd[t - off] : 0u;
        __syncthreads();
        if (t < 128) sd[t] += tmp;
        __syncthreads();
    }
    if (t < 128) {
        unsigned ex = sd[t] - v;
        loffs[t] = ex;
        beg_g[b * 128 + t] = base + ex;
        end_g[b * 128 + t] = base + ex + v;
    }
    __syncthreads();
    for (int i = t; i < cnt; i += 256) {
        float2 it = items[i];
        unsigned dl = __float_as_uint(it.y) >> 16;
        unsigned pos = atomicAdd(&lcur[dl], 1u);
        pair2[base + loffs[dl] + pos] = it;
    }
}

// ================= K4: 4-nodes-per-wave segment aggregate =================
__global__ __launch_bounds__(256) void k4_agg(const unsigned* __restrict__ beg_g,
                                              const unsigned* __restrict__ end_g,
                                              const float2* __restrict__ pair2,
                                              const __hip_bfloat16* __restrict__ zb,
                                              float* __restrict__ out) {
    const int t = threadIdx.x;
    const int lane = t & 63;
    const int sub = lane >> 4;               // node sub-index in wave
    const int lc = lane & 15;                // column group (cols lc*4 .. lc*4+3)
    const int wid = (blockIdx.x * 256 + t) >> 6;   // 0..12499
    const int n = wid * 4 + sub;             // 0..49999 (exact cover)
    const int lo = beg_g[n], hi = end_g[n];
    const ushort* zs = (const ushort*)zb;
    float a0 = 0.f, a1 = 0.f, a2 = 0.f, a3 = 0.f, den = 0.f;
    int i = lo;
    for (; i + 3 < hi; i += 4) {
        float2 pr[4];
#pragma unroll
        for (int j = 0; j < 4; ++j) pr[j] = pair2[i + j];
        ushort4 zv[4];
#pragma unroll
        for (int j = 0; j < 4; ++j) {
            int s = __float_as_uint(pr[j].y) & 0xFFFF;
            zv[j] = *(const ushort4*)&zs[s * OUT_DIM + lc * 4];
        }
#pragma unroll
        for (int j = 0; j < 4; ++j) {
            float e = __expf(pr[j].x);
            a0 += e * __uint_as_float((unsigned)zv[j].x << 16);
            a1 += e * __uint_as_float((unsigned)zv[j].y << 16);
            a2 += e * __uint_as_float((unsigned)zv[j].z << 16);
            a3 += e * __uint_as_float((unsigned)zv[j].w << 16);
            den += e;
        }
    }
    for (; i < hi; ++i) {
        float2 p0 = pair2[i];
        int s = __float_as_uint(p0.y) & 0xFFFF;
        ushort4 zv = *(const ushort4*)&zs[s * OUT_DIM + lc * 4];
        float e = __expf(p0.x);
        a0 += e * __uint_as_float((unsigned)zv.x << 16);
        a1 += e * __uint_as_float((unsigned)zv.y << 16);
        a2 += e * __uint_as_float((unsigned)zv.z << 16);
        a3 += e * __uint_as_float((unsigned)zv.w << 16);
        den += e;
    }
    float4 st;
    if (hi > lo) {
        float inv = 1.f / den;
        st.x = a0 * inv; st.y = a1 * inv; st.z = a2 * inv; st.w = a3 * inv;
    } else {
        st.x = st.y = st.z = st.w = 0.f;
    }
    ((float4*)out)[(size_t)n * 16 + lc] = st;
}

extern "C" void kernel_launch(void* const* d_in, const int* in_sizes, int n_in,
                              void* d_out, int out_size, void* d_ws, size_t ws_size,
                              hipStream_t stream) {
    const float* h     = (const float*)d_in[0];
    const float* p     = (const float*)d_in[1];
    const int*   src   = (const int*)d_in[2];
    const int*   dst   = (const int*)d_in[3];
    const float* Wfc   = (const float*)d_in[4];
    const float* Wattn = (const float*)d_in[5];
    float* out = (float*)d_out;

    // workspace layout (float words)
    float* ws = (float*)d_ws;
    __hip_bfloat16* zb = (__hip_bfloat16*)ws;        // 3,200,000 bf16 = 1,600,000 floats
    float*    s1     = ws + 1600000;                 // 50,000
    float*    s2     = ws + 1650000;                 // 50,000
    float*    dotp   = ws + 1700000;                 // 800,000
    unsigned* ccur   = (unsigned*)(ws + 2500000);    // 6,272 (391*16, 64B-strided)
    unsigned* beg_g  = (unsigned*)(ws + 2506272);    // 50,048
    unsigned* end_g  = (unsigned*)(ws + 2556320);    // 50,048
    float2*   pair   = (float2*)(ws + 2606368);      // NB*BWIN = 1,000,960 float2 (16B-aligned)
    float2*   pair2  = (float2*)(ws + 4608288);      // 1,000,960 float2 (16B-aligned)
    // total: 6,610,208 floats = 26.4 MB

    k12_fused<<<K12_GRID, 256, 0, stream>>>(h, Wfc, Wattn, p, zb, s1, s2, dotp, ccur);
    k3_fused<<<K3_BLOCKS, 256, 0, stream>>>(dotp, src, dst, s1, s2, ccur, pair);
    k3b_sort<<<NB, 256, 0, stream>>>(ccur, pair, pair2, beg_g, end_g);
    k4_agg<<<3125, 256, 0, stream>>>(beg_g, end_g, pair2, zb, out);
}

// Round 13
// 80.550 us; speedup vs baseline: 1.0069x; 1.0069x over previous
//
#include <hip/hip_runtime.h>
#include <hip/hip_bf16.h>

#define N_NODES 50000
#define N_EDGES 800000
#define IN_DIM 128
#define OUT_DIM 64
#define REL_DIM 32
#define NEG_SLOPE 0.01f
#define NB 391            // coarse buckets: 128 dst nodes each (391*128 = 50048)
#define K3_TILE 2048
#define K3_BLOCKS ((N_EDGES + K3_TILE - 1) / K3_TILE)   // 391
#define BWIN 2560         // fixed per-bucket window (Poisson(2048): max over 391 ~ 2200)
#define NBLK_A 782        // role-A blocks: ceil(50000/64)
#define K12_GRID 2346     // 3*NBLK_A; role A = blockIdx%3==0, else role B (1564 blocks)

// ================= K12 fused: GEMM (role A) || contiguous p-stream dotp (role B) ==============
// Role A: z = h @ Wfc^T register-tiled, K-quarter LDS tiles (17.4 KB).
// Role B: dotp[e] = wp . p[e] via lane-contiguous float4 stream + shfl8 reduce +
//         in-wave 8x8 transpose for one full-lane coalesced store per half.
// NOTE: no min-waves arg in launch_bounds — a VGPR cap of 32 (round 12) serialized
// role-B's 8-deep load window into dependent chains (latency collapse). ~64 VGPR +
// 17.4 KB LDS still reaches ~8 blocks/CU via wave slots.
__global__ __launch_bounds__(256) void k12_fused(const float* __restrict__ h,
                                                 const float* __restrict__ Wfc,
                                                 const float* __restrict__ Wattn,
                                                 const float* __restrict__ p,
                                                 __hip_bfloat16* __restrict__ zb,
                                                 float* __restrict__ s1,
                                                 float* __restrict__ s2,
                                                 float* __restrict__ dotp,
                                                 unsigned* __restrict__ ccur) {
    __shared__ float Wl[32][68];   // role A: [k_local][c]   (K-quarter)
    __shared__ float hl[32][68];   // role A: [k_local][n]
    const int t = threadIdx.x;
    const int b = blockIdx.x;

    if (b % 3 == 0) {
        // ---------------- role A: GEMM (4 K-quarters of 32) ----------------
        const int blk = b / 3;
        const int cg = t & 15, ng = t >> 4;
        const int c0 = cg * 4;
        float wa1[4], wa2[4];
#pragma unroll
        for (int j = 0; j < 4; ++j) { wa1[j] = Wattn[c0 + j]; wa2[j] = Wattn[96 + c0 + j]; }

        const int n0 = blk * 64;
        float acc[4][4] = {};
        const float4* W4 = (const float4*)Wfc;   // [64][32] float4
        const float4* h4 = (const float4*)h;     // [N][32] float4

#pragma unroll
        for (int Q = 0; Q < 4; ++Q) {
            __syncthreads();   // protect LDS from previous quarter's readers
#pragma unroll
            for (int i = 0; i < 2; ++i) {
                int idx = t + 256 * i;               // 0..511
                int c = idx & 63, k4l = idx >> 6;    // wave: 64 consecutive c, uniform k4l
                float4 v = W4[c * 32 + Q * 8 + k4l];
                Wl[4*k4l+0][c] = v.x; Wl[4*k4l+1][c] = v.y;
                Wl[4*k4l+2][c] = v.z; Wl[4*k4l+3][c] = v.w;
            }
#pragma unroll
            for (int i = 0; i < 2; ++i) {
                int idx = t + 256 * i;
                int n = idx & 63, k4l = idx >> 6;
                int gn = n0 + n; if (gn > N_NODES - 1) gn = N_NODES - 1;
                float4 v = h4[(size_t)gn * 32 + Q * 8 + k4l];
                hl[4*k4l+0][n] = v.x; hl[4*k4l+1][n] = v.y;
                hl[4*k4l+2][n] = v.z; hl[4*k4l+3][n] = v.w;
            }
            __syncthreads();
#pragma unroll 8
            for (int k = 0; k < 32; ++k) {
                float4 wv = *(const float4*)&Wl[k][c0];
                float4 hv = *(const float4*)&hl[k][ng * 4];
                float wvf[4] = {wv.x, wv.y, wv.z, wv.w};
                float hvf[4] = {hv.x, hv.y, hv.z, hv.w};
#pragma unroll
                for (int i = 0; i < 4; ++i)
#pragma unroll
                    for (int j = 0; j < 4; ++j) acc[i][j] += hvf[i] * wvf[j];
            }
        }

#pragma unroll
        for (int i = 0; i < 4; ++i) {
            int gn = n0 + ng * 4 + i;
            float r1 = acc[i][0]*wa1[0] + acc[i][1]*wa1[1] + acc[i][2]*wa1[2] + acc[i][3]*wa1[3];
            float r2 = acc[i][0]*wa2[0] + acc[i][1]*wa2[1] + acc[i][2]*wa2[2] + acc[i][3]*wa2[3];
#pragma unroll
            for (int off = 1; off < 16; off <<= 1) {
                r1 += __shfl_xor(r1, off, 64);
                r2 += __shfl_xor(r2, off, 64);
            }
            if (gn < N_NODES) {
                __hip_bfloat16 b0 = __float2bfloat16(acc[i][0]);
                __hip_bfloat16 b1 = __float2bfloat16(acc[i][1]);
                __hip_bfloat16 b2 = __float2bfloat16(acc[i][2]);
                __hip_bfloat16 b3 = __float2bfloat16(acc[i][3]);
                ushort4 st;
                st.x = *(unsigned short*)&b0; st.y = *(unsigned short*)&b1;
                st.z = *(unsigned short*)&b2; st.w = *(unsigned short*)&b3;
                ((ushort4*)zb)[(size_t)gn * 16 + cg] = st;
                if (cg == 0) { s1[gn] = r1; s2[gn] = r2; }
            }
        }
    } else {
        // ---------------- role B: contiguous dotp stream ----------------
        const int kb = b - b / 3 - 1;          // 0..1563
        if (kb == 0) {
            for (int i = t; i < NB * 16; i += 256) ccur[i] = 0u;
        }
        const int lane = t & 63;
        const int tid = kb * 256 + t;          // 0..400383
        const int a0 = (kb * 256 + (t & ~63)) >> 3;   // wave's base edge-slot (8 per wave)
        if (a0 < 50000) {                      // whole-wave guard (a0..a0+7 all < 50000)
            const int q = tid & 7;
            const float w0 = Wattn[64 + q * 4 + 0];
            const float w1 = Wattn[64 + q * 4 + 1];
            const float w2 = Wattn[64 + q * 4 + 2];
            const float w3 = Wattn[64 + q * 4 + 3];
            const float4* p4 = (const float4*)p;
#pragma unroll
            for (int half = 0; half < 2; ++half) {
                float4 v[8];
#pragma unroll
                for (int j = 0; j < 8; ++j) v[j] = p4[tid + (half * 8 + j) * 400000];
                float d[8];
#pragma unroll
                for (int j = 0; j < 8; ++j)
                    d[j] = v[j].x * w0 + v[j].y * w1 + v[j].z * w2 + v[j].w * w3;
#pragma unroll
                for (int off = 1; off < 8; off <<= 1)
#pragma unroll
                    for (int j = 0; j < 8; ++j) d[j] += __shfl_xor(d[j], off, 64);
                // in-wave 8x8 transpose: lane l takes d[l>>3] from group (l&7)
                float val = 0.f;
#pragma unroll
                for (int j = 0; j < 8; ++j) {
                    float tmp = __shfl(d[j], (lane & 7) * 8, 64);
                    if ((lane >> 3) == j) val = tmp;
                }
                // one coalesced store: 8-lane groups write 32B-contiguous segments
                dotp[a0 + (lane & 7) + (half * 8 + (lane >> 3)) * 50000] = val;
            }
        }
    }
}

// ================= K3: logit assembly + leaky-relu + binning into fixed bucket windows ========
// pair item: (ev, aux) with aux = src | (d_local << 16)
__global__ __launch_bounds__(256) void k3_fused(const float* __restrict__ dotp,
                                                const int* __restrict__ src,
                                                const int* __restrict__ dst,
                                                const float* __restrict__ s1,
                                                const float* __restrict__ s2,
                                                unsigned* __restrict__ ccur,
                                                float2* __restrict__ pair) {
    __shared__ unsigned hist[NB];
    __shared__ unsigned gb[NB];
    __shared__ unsigned lcur[NB];
    const int t = threadIdx.x;
    for (int i = t; i < NB; i += 256) hist[i] = 0;
    __syncthreads();

    const int base = blockIdx.x * K3_TILE;
    float evr[8];
    unsigned auxr[8];
    short br[8];
#pragma unroll
    for (int i = 0; i < 8; ++i) {
        int e = base + i * 256 + t;
        if (e < N_EDGES) {
            int s = src[e], d = dst[e];
            float a = s1[s] + dotp[e] + s2[d];
            evr[i] = a > 0.f ? a : NEG_SLOPE * a;
            auxr[i] = (unsigned)s | ((unsigned)(d & 127) << 16);
            int bb = d >> 7;
            br[i] = (short)bb;
            atomicAdd(&hist[bb], 1u);
        } else br[i] = -1;
    }
    __syncthreads();
    for (int i = t; i < NB; i += 256) {
        lcur[i] = 0;
        gb[i] = hist[i] ? (i * BWIN + atomicAdd(&ccur[i * 16], hist[i])) : 0u;
    }
    __syncthreads();
#pragma unroll
    for (int i = 0; i < 8; ++i) {
        if (br[i] >= 0) {
            int bb = br[i];
            unsigned pos = atomicAdd(&lcur[bb], 1u);
            pair[gb[bb] + pos] = make_float2(evr[i], __uint_as_float(auxr[i]));
        }
    }
}

// ================= K3b: within-bucket sort to per-node order + per-node beg/end ===============
__global__ __launch_bounds__(256) void k3b_sort(const unsigned* __restrict__ ccur,
                                                const float2* __restrict__ pair,
                                                float2* __restrict__ pair2,
                                                unsigned* __restrict__ beg_g,
                                                unsigned* __restrict__ end_g) {
    __shared__ float2 items[BWIN];          // 20.5KB
    __shared__ unsigned hist[128], loffs[128], lcur[128], sd[128];
    const int t = threadIdx.x;
    const int b = blockIdx.x;
    const int base = b * BWIN;
    int cnt = (int)ccur[b * 16];
    if (cnt > BWIN) cnt = BWIN;             // safety clamp (deterministic input: never hit)
    if (t < 128) { hist[t] = 0; lcur[t] = 0; }
    __syncthreads();
    for (int i = t; i < cnt; i += 256) {
        float2 it = pair[base + i];
        items[i] = it;
        atomicAdd(&hist[__float_as_uint(it.y) >> 16], 1u);
    }
    __syncthreads();
    unsigned v = (t < 128) ? hist[t] : 0u;
    if (t < 128) sd[t] = v;
    __syncthreads();
#pragma unroll
    for (int off = 1; off < 128; off <<= 1) {
        unsigned tmp = (t >= off && t < 128) ? sd[t - off] : 0u;
        __syncthreads();
        if (t < 128) sd[t] += tmp;
        __syncthreads();
    }
    if (t < 128) {
        unsigned ex = sd[t] - v;
        loffs[t] = ex;
        beg_g[b * 128 + t] = base + ex;
        end_g[b * 128 + t] = base + ex + v;
    }
    __syncthreads();
    for (int i = t; i < cnt; i += 256) {
        float2 it = items[i];
        unsigned dl = __float_as_uint(it.y) >> 16;
        unsigned pos = atomicAdd(&lcur[dl], 1u);
        pair2[base + loffs[dl] + pos] = it;
    }
}

// ================= K4: 4-nodes-per-wave segment aggregate =================
__global__ __launch_bounds__(256) void k4_agg(const unsigned* __restrict__ beg_g,
                                              const unsigned* __restrict__ end_g,
                                              const float2* __restrict__ pair2,
                                              const __hip_bfloat16* __restrict__ zb,
                                              float* __restrict__ out) {
    const int t = threadIdx.x;
    const int lane = t & 63;
    const int sub = lane >> 4;               // node sub-index in wave
    const int lc = lane & 15;                // column group (cols lc*4 .. lc*4+3)
    const int wid = (blockIdx.x * 256 + t) >> 6;   // 0..12499
    const int n = wid * 4 + sub;             // 0..49999 (exact cover)
    const int lo = beg_g[n], hi = end_g[n];
    const ushort* zs = (const ushort*)zb;
    float a0 = 0.f, a1 = 0.f, a2 = 0.f, a3 = 0.f, den = 0.f;
    int i = lo;
    for (; i + 3 < hi; i += 4) {
        float2 pr[4];
#pragma unroll
        for (int j = 0; j < 4; ++j) pr[j] = pair2[i + j];
        ushort4 zv[4];
#pragma unroll
        for (int j = 0; j < 4; ++j) {
            int s = __float_as_uint(pr[j].y) & 0xFFFF;
            zv[j] = *(const ushort4*)&zs[s * OUT_DIM + lc * 4];
        }
#pragma unroll
        for (int j = 0; j < 4; ++j) {
            float e = __expf(pr[j].x);
            a0 += e * __uint_as_float((unsigned)zv[j].x << 16);
            a1 += e * __uint_as_float((unsigned)zv[j].y << 16);
            a2 += e * __uint_as_float((unsigned)zv[j].z << 16);
            a3 += e * __uint_as_float((unsigned)zv[j].w << 16);
            den += e;
        }
    }
    for (; i < hi; ++i) {
        float2 p0 = pair2[i];
        int s = __float_as_uint(p0.y) & 0xFFFF;
        ushort4 zv = *(const ushort4*)&zs[s * OUT_DIM + lc * 4];
        float e = __expf(p0.x);
        a0 += e * __uint_as_float((unsigned)zv.x << 16);
        a1 += e * __uint_as_float((unsigned)zv.y << 16);
        a2 += e * __uint_as_float((unsigned)zv.z << 16);
        a3 += e * __uint_as_float((unsigned)zv.w << 16);
        den += e;
    }
    float4 st;
    if (hi > lo) {
        float inv = 1.f / den;
        st.x = a0 * inv; st.y = a1 * inv; st.z = a2 * inv; st.w = a3 * inv;
    } else {
        st.x = st.y = st.z = st.w = 0.f;
    }
    ((float4*)out)[(size_t)n * 16 + lc] = st;
}

extern "C" void kernel_launch(void* const* d_in, const int* in_sizes, int n_in,
                              void* d_out, int out_size, void* d_ws, size_t ws_size,
                              hipStream_t stream) {
    const float* h     = (const float*)d_in[0];
    const float* p     = (const float*)d_in[1];
    const int*   src   = (const int*)d_in[2];
    const int*   dst   = (const int*)d_in[3];
    const float* Wfc   = (const float*)d_in[4];
    const float* Wattn = (const float*)d_in[5];
    float* out = (float*)d_out;

    // workspace layout (float words)
    float* ws = (float*)d_ws;
    __hip_bfloat16* zb = (__hip_bfloat16*)ws;        // 3,200,000 bf16 = 1,600,000 floats
    float*    s1     = ws + 1600000;                 // 50,000
    float*    s2     = ws + 1650000;                 // 50,000
    float*    dotp   = ws + 1700000;                 // 800,000
    unsigned* ccur   = (unsigned*)(ws + 2500000);    // 6,272 (391*16, 64B-strided)
    unsigned* beg_g  = (unsigned*)(ws + 2506272);    // 50,048
    unsigned* end_g  = (unsigned*)(ws + 2556320);    // 50,048
    float2*   pair   = (float2*)(ws + 2606368);      // NB*BWIN = 1,000,960 float2 (16B-aligned)
    float2*   pair2  = (float2*)(ws + 4608288);      // 1,000,960 float2 (16B-aligned)
    // total: 6,610,208 floats = 26.4 MB

    k12_fused<<<K12_GRID, 256, 0, stream>>>(h, Wfc, Wattn, p, zb, s1, s2, dotp, ccur);
    k3_fused<<<K3_BLOCKS, 256, 0, stream>>>(dotp, src, dst, s1, s2, ccur, pair);
    k3b_sort<<<NB, 256, 0, stream>>>(ccur, pair, pair2, beg_g, end_g);
    k4_agg<<<3125, 256, 0, stream>>>(beg_g, end_g, pair2, zb, out);
}